// Round 8
// baseline (274.615 us; speedup 1.0000x reference)
//
#include <hip/hip_runtime.h>

#define DIN 256
#define DH  64
#define DOUT 4
#define CAP 32   // bucket capacity; P(any node deg>=32 | E=320k,N=100k) ~ 1e-14

typedef __attribute__((ext_vector_type(8))) short bf16x8;
typedef __attribute__((ext_vector_type(4))) float f32x4;

__device__ __forceinline__ short f2bf(float f) {       // RNE (used in wprep only)
    unsigned int u = __float_as_uint(f);
    unsigned int r = (u + 0x7FFFu + ((u >> 16) & 1u)) >> 16;
    return (short)r;
}
__device__ __forceinline__ short f2bf_trunc(float f) { // truncate mantissa
    return (short)(__float_as_uint(f) >> 16);
}
__device__ __forceinline__ float bf2f(short h) {
    return __uint_as_float(((unsigned int)(unsigned short)h) << 16);
}

// ===========================================================================
// fillprep: ONE dispatch replacing {count, scans, fill, wprep}.
//  - blocks [0, FB):  bucket scatter: cnt[d] becomes degree, bucket[d][p]=src
//  - blocks [FB, FB+128): wprep role (W split-bf16 transpose), independent
// ===========================================================================
__global__ void fillprep_kernel(const int* __restrict__ src, const int* __restrict__ dst,
                                int* __restrict__ cnt, int* __restrict__ bucket,
                                const float* __restrict__ Wl, const float* __restrict__ Wr,
                                short* __restrict__ WTh, short* __restrict__ WTl,
                                int E, int FB)
{
    if ((int)blockIdx.x >= FB) {
        const int n = blockIdx.x - FB;   // 0..127
        const int k = threadIdx.x;       // 0..255
        const float v = (n < 64) ? Wl[k * 64 + n] : Wr[k * 64 + (n - 64)];
        const short hi = f2bf(v);
        const short lo = f2bf(v - bf2f(hi));
        WTh[n * 256 + k] = hi;
        WTl[n * 256 + k] = lo;
        return;
    }
    const int e = blockIdx.x * 256 + threadIdx.x;
    if (e >= E) return;
    const int d = dst[e];
    const int p = atomicAdd(&cnt[d], 1);
    if (p < CAP) bucket[(size_t)d * CAP + p] = src[e];
}

// ===========================================================================
// GEMM1 v6 (split-bf16 MFMA): y[N,128] = x[N,256] @ [W1_l | W1_r].
// Whole-tile staging for memory-level parallelism: each block stages its
// ENTIRE 32-row x 256-col fp32 x-tile (32 KB) via global_load_lds in one
// burst (8 issues/wave), ONE barrier, then 8 K-chunks of pure LDS+MFMA with
// convert-on-read (raw fp32 -> hi/lo bf16 in regs; no bf16 LDS round-trip).
// 4 blocks/CU alternate stage/compute -> HBM queue stays full (~130 KB/CU
// outstanding vs ~8 KB burst in v2). W register-double-buffered from L2.
// Same element mapping + f2bf math + MFMA order as v2 -> bit-identical y.
// Block: 32 rows x 128 cols, 256 threads (4 waves, wave w = cols w*32..+32).
// ===========================================================================
#define RX_LD 260   // 256 + 4 pad floats; row stride 1040 B (16B-aligned)
__global__ __launch_bounds__(256, 4) void gemm1_mfma(
    const float* __restrict__ x, const short* __restrict__ WTh,
    const short* __restrict__ WTl, float* __restrict__ y, int N)
{
    __shared__ float rawx[32 * RX_LD];   // 33280 B

    const int tid  = threadIdx.x;
    const int wave = tid >> 6;
    const int lane = tid & 63;
    const int lm   = lane & 15;
    const int quad = lane >> 4;
    const int brow = blockIdx.x * 32;

    // ---- stage the whole x-tile: wave w stages rows w*8..w*8+7 (1 KB each)
    {
        const int srow = wave * 8;
        #pragma unroll
        for (int j = 0; j < 8; ++j) {
            const int rowg = min(brow + srow + j, N - 1);   // clamp (N%32==0 normally)
            __builtin_amdgcn_global_load_lds(
                (const __attribute__((address_space(1))) unsigned int*)
                    (x + (size_t)rowg * DIN + lane * 4),
                (__attribute__((address_space(3))) unsigned int*)
                    &rawx[(srow + j) * RX_LD],
                16, 0, 0);
        }
    }

    // ---- W fragment global offsets (per lane, per N-tile)
    const int col0 = wave * 32 + lm;
    const size_t wb0 = (size_t)col0 * 256 + quad * 8;
    const size_t wb1 = (size_t)(col0 + 16) * 256 + quad * 8;

    f32x4 acc[2][2];
    #pragma unroll
    for (int mt = 0; mt < 2; ++mt)
        #pragma unroll
        for (int nt = 0; nt < 2; ++nt)
            acc[mt][nt] = (f32x4){0.f, 0.f, 0.f, 0.f};

    // W chunk 0 (arrives under the staging wait)
    bf16x8 wh_cur[2], wl_cur[2];
    wh_cur[0] = *(const bf16x8*)(WTh + wb0);
    wh_cur[1] = *(const bf16x8*)(WTh + wb1);
    wl_cur[0] = *(const bf16x8*)(WTl + wb0);
    wl_cur[1] = *(const bf16x8*)(WTl + wb1);

    __syncthreads();   // drains vmcnt(0): whole tile + W0 landed. ONE barrier.

    #pragma unroll
    for (int k = 0; k < 8; ++k) {
        // ---- prefetch W chunk k+1 (L2-resident, lands under MFMAs)
        bf16x8 wh_nxt[2], wl_nxt[2];
        if (k < 7) {
            const int kc = (k + 1) * 32;
            wh_nxt[0] = *(const bf16x8*)(WTh + wb0 + kc);
            wh_nxt[1] = *(const bf16x8*)(WTh + wb1 + kc);
            wl_nxt[0] = *(const bf16x8*)(WTl + wb0 + kc);
            wl_nxt[1] = *(const bf16x8*)(WTl + wb1 + kc);
        }

        // ---- compute chunk k: convert-on-read from raw fp32 LDS
        #pragma unroll
        for (int mt = 0; mt < 2; ++mt) {
            const float* rp = &rawx[(mt * 16 + lm) * RX_LD + k * 32 + quad * 8];
            const float4 r0 = ((const float4*)rp)[0];
            const float4 r1 = ((const float4*)rp)[1];
            bf16x8 ah, al;
            {
                float fv[8] = {r0.x, r0.y, r0.z, r0.w, r1.x, r1.y, r1.z, r1.w};
                #pragma unroll
                for (int j = 0; j < 8; ++j) {
                    const short hi = f2bf_trunc(fv[j]);
                    ah[j] = hi;
                    al[j] = f2bf_trunc(fv[j] - bf2f(hi));
                }
            }
            #pragma unroll
            for (int nt = 0; nt < 2; ++nt) {
                acc[mt][nt] = __builtin_amdgcn_mfma_f32_16x16x32_bf16(
                    ah, wh_cur[nt], acc[mt][nt], 0, 0, 0);
                acc[mt][nt] = __builtin_amdgcn_mfma_f32_16x16x32_bf16(
                    ah, wl_cur[nt], acc[mt][nt], 0, 0, 0);
                acc[mt][nt] = __builtin_amdgcn_mfma_f32_16x16x32_bf16(
                    al, wh_cur[nt], acc[mt][nt], 0, 0, 0);
            }
        }

        if (k < 7) {
            #pragma unroll
            for (int nt = 0; nt < 2; ++nt) {
                wh_cur[nt] = wh_nxt[nt];
                wl_cur[nt] = wl_nxt[nt];
            }
        }
    }

    // ---- epilogue: C/D layout col=lane&15, row=quad*4+reg
    #pragma unroll
    for (int mt = 0; mt < 2; ++mt) {
        #pragma unroll
        for (int r = 0; r < 4; ++r) {
            const int rg = brow + mt * 16 + quad * 4 + r;
            if (rg < N) {
                const int col = wave * 32 + lm;
                float* yp = y + (size_t)rg * 128 + col;
                yp[0]  = acc[mt][0][r];
                yp[16] = acc[mt][1][r];
            }
        }
    }
}

// ===========================================================================
// gemm2 inline butterfly: lane f holds h[f]; returns this lane's channel sum.
// ===========================================================================
__device__ __forceinline__ float gemm2_butterfly(float hv, float4 wl, float4 wr, int lane) {
    float p0 = hv * wl.x, p1 = hv * wl.y, p2 = hv * wl.z, p3 = hv * wl.w;
    float p4 = hv * wr.x, p5 = hv * wr.y, p6 = hv * wr.z, p7 = hv * wr.w;
    const bool b0 = (lane & 1) != 0;
    float s0_ = b0 ? p0 : p4;
    float s1_ = b0 ? p1 : p5;
    float s2_ = b0 ? p2 : p6;
    float s3_ = b0 ? p3 : p7;
    float q0 = (b0 ? p4 : p0) + __shfl_xor(s0_, 1, 64);
    float q1 = (b0 ? p5 : p1) + __shfl_xor(s1_, 1, 64);
    float q2 = (b0 ? p6 : p2) + __shfl_xor(s2_, 1, 64);
    float q3 = (b0 ? p7 : p3) + __shfl_xor(s3_, 1, 64);
    const bool b1b = (lane & 2) != 0;
    float t0 = b1b ? q0 : q2;
    float t1 = b1b ? q1 : q3;
    float r0 = (b1b ? q2 : q0) + __shfl_xor(t0, 2, 64);
    float r1 = (b1b ? q3 : q1) + __shfl_xor(t1, 2, 64);
    const bool b2 = (lane & 4) != 0;
    float u0 = b2 ? r0 : r1;
    float zv = (b2 ? r1 : r0) + __shfl_xor(u0, 4, 64);
    zv += __shfl_xor(zv, 8, 64);
    zv += __shfl_xor(zv, 16, 64);
    zv += __shfl_xor(zv, 32, 64);
    return zv;
}

// ===========================================================================
// fused1 v2: TWO nodes per wave for 2x memory-level parallelism.
// ===========================================================================
__global__ __launch_bounds__(256) void fused1_kernel(
    const float* __restrict__ y, const int* __restrict__ cnt, const int* __restrict__ bucket,
    const float* __restrict__ b1, const float* __restrict__ W2l, const float* __restrict__ W2r,
    float* __restrict__ z, int N)
{
    const int wave = threadIdx.x >> 6;
    const int lane = threadIdx.x & 63;
    const int half = lane >> 5;          // 0 -> node A, 1 -> node B
    const int l5   = lane & 31;
    const int base = (blockIdx.x * 4 + wave) * 2;
    if (base >= N) return;
    const int iA = base;
    const bool hasB = (base + 1 < N);
    const int iB = hasB ? base + 1 : base;

    const int degA = cnt[iA];
    const int degB = cnt[iB];
    const int ddA = (degA < CAP) ? degA : CAP;
    const int ddB = (degB < CAP) ? degB : CAP;

    // one coalesced load: both nodes' neighbor lists (rows are contiguous)
    const int myn = bucket[(size_t)(half ? iB : iA) * CAP + l5];

    float accA = 0.f, accB = 0.f;
    const int jm = (ddA > ddB) ? ddA : ddB;
    for (int j = 0; j < jm; j += 2) {
        const int sA0 = __shfl(myn, j, 64);
        const int sA1 = __shfl(myn, j + 1, 64);
        const int sB0 = __shfl(myn, 32 + j, 64);
        const int sB1 = __shfl(myn, 33 + j, 64);
        const int cA0 = (j     < ddA) ? sA0 : 0;
        const int cA1 = (j + 1 < ddA) ? sA1 : 0;
        const int cB0 = (j     < ddB) ? sB0 : 0;
        const int cB1 = (j + 1 < ddB) ? sB1 : 0;
        const float vA0 = y[(size_t)cA0 * 128 + lane];
        const float vA1 = y[(size_t)cA1 * 128 + lane];
        const float vB0 = y[(size_t)cB0 * 128 + lane];
        const float vB1 = y[(size_t)cB1 * 128 + lane];
        if (j + 1 < ddA)  accA += vA0 + vA1;    // same pairing as r0
        else if (j < ddA) accA += vA0;
        if (j + 1 < ddB)  accB += vB0 + vB1;
        else if (j < ddB) accB += vB0;
    }

    const float dinvA = 1.0f / fmaxf((float)degA, 1.0f);
    const float dinvB = 1.0f / fmaxf((float)degB, 1.0f);
    const float bl = b1[lane];
    float vA = accA * dinvA + bl + y[(size_t)iA * 128 + 64 + lane];
    float vB = accB * dinvB + bl + y[(size_t)iB * 128 + 64 + lane];

    float ssA = vA * vA, ssB = vB * vB;
    #pragma unroll
    for (int m = 32; m >= 1; m >>= 1) {
        ssA += __shfl_xor(ssA, m, 64);
        ssB += __shfl_xor(ssB, m, 64);
    }
    const float invA = 1.0f / fmaxf(sqrtf(ssA), 1e-12f);
    const float invB = 1.0f / fmaxf(sqrtf(ssB), 1e-12f);
    const float hvA = fmaxf(vA * invA, 0.f);
    const float hvB = fmaxf(vB * invB, 0.f);

    const float4 wl = *(const float4*)(W2l + lane * 4);
    const float4 wr = *(const float4*)(W2r + lane * 4);
    const float zvA = gemm2_butterfly(hvA, wl, wr, lane);
    const float zvB = gemm2_butterfly(hvB, wl, wr, lane);

    const int ch = 4 * (lane & 1) + (lane & 2) + ((lane >> 2) & 1);
    if (lane < 8) {
        z[(size_t)iA * 8 + ch] = zvA;
        if (hasB) z[(size_t)iB * 8 + ch] = zvB;
    }
}

// ===========================================================================
// fused2 v2: batched 8-wide prefetch of neighbor z-rows into registers.
// ===========================================================================
__global__ void fused2_kernel(const float* __restrict__ z, const int* __restrict__ cnt,
                              const int* __restrict__ bucket, const float* __restrict__ b2,
                              float* __restrict__ out, int N)
{
    const int i = blockIdx.x * blockDim.x + threadIdx.x;
    if (i >= N) return;
    const int deg = cnt[i];
    const int dd = (deg < CAP) ? deg : CAP;

    float4 t[8];
    #pragma unroll
    for (int j = 0; j < 8; ++j) {
        int s = bucket[(size_t)i * CAP + ((j < dd) ? j : 0)];
        s = (j < dd) ? s : i;                    // safe address for unused slots
        t[j] = *(const float4*)(z + (size_t)s * 8);
    }

    float4 acc = make_float4(0.f, 0.f, 0.f, 0.f);
    #pragma unroll
    for (int j = 0; j < 8; ++j) {
        if (j < dd) {
            acc.x += t[j].x; acc.y += t[j].y; acc.z += t[j].z; acc.w += t[j].w;
        }
    }
    for (int j = 8; j < dd; ++j) {               // rare tail (P ~ 0.6%)
        const int s = bucket[(size_t)i * CAP + j];
        const float4 u = *(const float4*)(z + (size_t)s * 8);
        acc.x += u.x; acc.y += u.y; acc.z += u.z; acc.w += u.w;
    }

    const float dinv = 1.0f / fmaxf((float)deg, 1.0f);
    const float4 r  = *(const float4*)(z + (size_t)i * 8 + 4);
    const float4 bb = *(const float4*)(b2);
    float4 o;
    o.x = acc.x * dinv + bb.x + r.x;
    o.y = acc.y * dinv + bb.y + r.y;
    o.z = acc.z * dinv + bb.z + r.z;
    o.w = acc.w * dinv + bb.w + r.w;
    const float ss = o.x * o.x + o.y * o.y + o.z * o.z + o.w * o.w;
    const float inv = 1.0f / fmaxf(sqrtf(ss), 1e-12f);
    o.x *= inv; o.y *= inv; o.z *= inv; o.w *= inv;
    *(float4*)(out + (size_t)i * 4) = o;
}

// ===========================================================================
extern "C" void kernel_launch(void* const* d_in, const int* in_sizes, int n_in,
                              void* d_out, int out_size, void* d_ws, size_t ws_size,
                              hipStream_t stream)
{
    const float* x    = (const float*)d_in[0];
    const int*   ei   = (const int*)d_in[1];
    const float* W1l  = (const float*)d_in[2];
    const float* b1l  = (const float*)d_in[3];
    const float* W1r  = (const float*)d_in[4];
    const float* W2l  = (const float*)d_in[5];
    const float* b2l  = (const float*)d_in[6];
    const float* W2r  = (const float*)d_in[7];
    float* out = (float*)d_out;

    const int N = in_sizes[0] / DIN;
    const int E = in_sizes[1] / 2;
    const int* src = ei;
    const int* dst = ei + E;

    // workspace layout
    char* ws = (char*)d_ws;
    size_t woff = 0;
    auto alloc = [&](size_t bytes) {
        void* p = ws + woff;
        woff += (bytes + 255) & ~(size_t)255;
        return p;
    };
    float* y      = (float*)alloc((size_t)N * 128 * 4);
    float* z      = (float*)alloc((size_t)N * 8 * 4);
    short* WTh    = (short*)alloc((size_t)128 * 256 * 2);
    short* WTl    = (short*)alloc((size_t)128 * 256 * 2);
    int*   cnt    = (int*)alloc((size_t)N * 4);
    int*   bucket = (int*)alloc((size_t)N * CAP * 4);

    hipMemsetAsync(cnt, 0, (size_t)N * 4, stream);

    // --- CSR-bucket build + W prep (single dispatch, role-split grid)
    const int FB = (E + 255) / 256;
    fillprep_kernel<<<FB + 128, 256, 0, stream>>>(src, dst, cnt, bucket,
                                                  W1l, W1r, WTh, WTl, E, FB);

    // --- layer 1 GEMM (whole-tile staging, 1 barrier/block)
    gemm1_mfma<<<(N + 31) / 32, 256, 0, stream>>>(x, WTh, WTl, y, N);

    // --- fused aggregate + norm + relu + gemm2 (2 nodes/wave, 2x MLP)
    fused1_kernel<<<(N + 7) / 8, 256, 0, stream>>>(y, cnt, bucket, b1l, W2l, W2r, z, N);

    // --- fused aggregate + norm (layer 2, batched prefetch)
    fused2_kernel<<<(N + 255) / 256, 256, 0, stream>>>(z, cnt, bucket, b2l, out, N);
}

// Round 9
// 235.607 us; speedup vs baseline: 1.1656x; 1.1656x over previous
//
#include <hip/hip_runtime.h>

#define DIN 256
#define DH  64
#define DOUT 4
#define CAP 32   // bucket capacity; P(any node deg>=32 | E=320k,N=100k) ~ 1e-14

typedef __attribute__((ext_vector_type(8))) short bf16x8;
typedef __attribute__((ext_vector_type(4))) float f32x4;

__device__ __forceinline__ short f2bf(float f) {       // RNE (used in wprep only)
    unsigned int u = __float_as_uint(f);
    unsigned int r = (u + 0x7FFFu + ((u >> 16) & 1u)) >> 16;
    return (short)r;
}
__device__ __forceinline__ short f2bf_trunc(float f) { // truncate mantissa
    return (short)(__float_as_uint(f) >> 16);
}
__device__ __forceinline__ float bf2f(short h) {
    return __uint_as_float(((unsigned int)(unsigned short)h) << 16);
}

// ===========================================================================
// wprep_zero: dispatch 1. blocks [0,128): W split-bf16 transpose.
//             blocks [128, 128+ZB): zero cnt (replaces hipMemsetAsync).
// ===========================================================================
__global__ void wprep_zero_kernel(const float* __restrict__ Wl, const float* __restrict__ Wr,
                                  short* __restrict__ WTh, short* __restrict__ WTl,
                                  int* __restrict__ cnt, int N)
{
    if ((int)blockIdx.x < 128) {
        const int n = blockIdx.x;    // 0..127
        const int k = threadIdx.x;   // 0..255
        const float v = (n < 64) ? Wl[k * 64 + n] : Wr[k * 64 + (n - 64)];
        const short hi = f2bf(v);
        const short lo = f2bf(v - bf2f(hi));
        WTh[n * 256 + k] = hi;
        WTl[n * 256 + k] = lo;
        return;
    }
    const int t4 = (blockIdx.x - 128) * 256 + threadIdx.x;
    const int n4 = N >> 2;
    if (t4 < n4) ((int4*)cnt)[t4] = make_int4(0, 0, 0, 0);
    if (t4 == 0)
        for (int r = N & ~3; r < N; ++r) cnt[r] = 0;
}

// ===========================================================================
// GEMM1 + edge scatter, ONE dispatch. GEMM blocks FIRST [0,NB) so they flood
// the CUs; scatter blocks [NB,NB+SB) trail and fill as GEMM blocks retire
// (r5 failure inverted: scatter-first serialized). __launch_bounds__(256,4)
// keeps the proven 60-VGPR GEMM codegen (r5's (256,6) forced a 40-VGPR
// rebuild that regressed).
// GEMM: r0-exact v2 body: y[N,128] = x[N,256] @ [W1_l|W1_r], split-bf16 MFMA,
// 64 rows x 128 cols per block, BK=32, 4 waves, bit-identical output.
// ===========================================================================
#define XS_LD 40   // 32 + 8 pad (bf16 elems); 80 B row stride
__global__ __launch_bounds__(256, 4) void gemm_scatter_kernel(
    const float* __restrict__ x, const short* __restrict__ WTh,
    const short* __restrict__ WTl, float* __restrict__ y,
    const int* __restrict__ src, const int* __restrict__ dst,
    int* __restrict__ cnt, int* __restrict__ bucket,
    int N, int E, int NB)
{
    __shared__ short xsh[2][64 * XS_LD];   // 2 x 5120 B
    __shared__ short xsl[2][64 * XS_LD];

    // ---------------- scatter role (trailing blocks) ----------------
    if ((int)blockIdx.x >= NB) {
        const int e = ((int)blockIdx.x - NB) * 256 + threadIdx.x;
        if (e < E) {
            const int d = dst[e];
            const int p = atomicAdd(&cnt[d], 1);
            if (p < CAP) bucket[(size_t)d * CAP + p] = src[e];
        }
        return;
    }

    // ---------------- GEMM role (r0-exact v2 body) ----------------
    const int tid  = threadIdx.x;
    const int wave = tid >> 6;
    const int lane = tid & 63;
    const int lm   = lane & 15;
    const int quad = lane >> 4;
    const int brow = blockIdx.x * 64;

    const int xr    = tid >> 2;           // 0..63
    const int xk    = (tid & 3) * 8;      // 0/8/16/24
    const int row_g = brow + xr;
    const bool xvalid = (row_g < N);
    const float* xptr = x + (size_t)row_g * DIN + xk;
    const int xs_off = xr * XS_LD + xk;

    const int col0 = wave * 32 + lm;
    const size_t wb0 = (size_t)col0 * 256 + quad * 8;
    const size_t wb1 = (size_t)(col0 + 16) * 256 + quad * 8;

    f32x4 acc[4][2];
    #pragma unroll
    for (int mt = 0; mt < 4; ++mt)
        #pragma unroll
        for (int nt = 0; nt < 2; ++nt)
            acc[mt][nt] = (f32x4){0.f, 0.f, 0.f, 0.f};

    {
        float4 a, b;
        if (xvalid) {
            a = ((const float4*)xptr)[0];
            b = ((const float4*)xptr)[1];
        } else {
            a = b = make_float4(0.f, 0.f, 0.f, 0.f);
        }
        bf16x8 ph, pl;
        float fv[8] = {a.x, a.y, a.z, a.w, b.x, b.y, b.z, b.w};
        #pragma unroll
        for (int j = 0; j < 8; ++j) {
            const short hi = f2bf_trunc(fv[j]);
            ph[j] = hi;
            pl[j] = f2bf_trunc(fv[j] - bf2f(hi));
        }
        *(bf16x8*)(&xsh[0][xs_off]) = ph;
        *(bf16x8*)(&xsl[0][xs_off]) = pl;
    }
    bf16x8 wh_cur[2], wl_cur[2];
    wh_cur[0] = *(const bf16x8*)(WTh + wb0);
    wh_cur[1] = *(const bf16x8*)(WTh + wb1);
    wl_cur[0] = *(const bf16x8*)(WTl + wb0);
    wl_cur[1] = *(const bf16x8*)(WTl + wb1);
    __syncthreads();

    #pragma unroll
    for (int k = 0; k < 8; ++k) {
        const int buf = k & 1;

        float4 na, nb;
        bf16x8 wh_nxt[2], wl_nxt[2];
        if (k < 7) {
            const int kc = (k + 1) * 32;
            if (xvalid) {
                na = ((const float4*)(xptr + kc))[0];
                nb = ((const float4*)(xptr + kc))[1];
            } else {
                na = nb = make_float4(0.f, 0.f, 0.f, 0.f);
            }
            wh_nxt[0] = *(const bf16x8*)(WTh + wb0 + kc);
            wh_nxt[1] = *(const bf16x8*)(WTh + wb1 + kc);
            wl_nxt[0] = *(const bf16x8*)(WTl + wb0 + kc);
            wl_nxt[1] = *(const bf16x8*)(WTl + wb1 + kc);
        }

        #pragma unroll
        for (int mt = 0; mt < 4; ++mt) {
            const int aoff = (mt * 16 + lm) * XS_LD + quad * 8;
            const bf16x8 ah = *(const bf16x8*)(&xsh[buf][aoff]);
            const bf16x8 al = *(const bf16x8*)(&xsl[buf][aoff]);
            #pragma unroll
            for (int nt = 0; nt < 2; ++nt) {
                acc[mt][nt] = __builtin_amdgcn_mfma_f32_16x16x32_bf16(
                    ah, wh_cur[nt], acc[mt][nt], 0, 0, 0);
                acc[mt][nt] = __builtin_amdgcn_mfma_f32_16x16x32_bf16(
                    ah, wl_cur[nt], acc[mt][nt], 0, 0, 0);
                acc[mt][nt] = __builtin_amdgcn_mfma_f32_16x16x32_bf16(
                    al, wh_cur[nt], acc[mt][nt], 0, 0, 0);
            }
        }

        if (k < 7) {
            bf16x8 ph, pl;
            float fv[8] = {na.x, na.y, na.z, na.w, nb.x, nb.y, nb.z, nb.w};
            #pragma unroll
            for (int j = 0; j < 8; ++j) {
                const short hi = f2bf_trunc(fv[j]);
                ph[j] = hi;
                pl[j] = f2bf_trunc(fv[j] - bf2f(hi));
            }
            *(bf16x8*)(&xsh[buf ^ 1][xs_off]) = ph;
            *(bf16x8*)(&xsl[buf ^ 1][xs_off]) = pl;
            #pragma unroll
            for (int nt = 0; nt < 2; ++nt) {
                wh_cur[nt] = wh_nxt[nt];
                wl_cur[nt] = wl_nxt[nt];
            }
            __syncthreads();
        }
    }

    #pragma unroll
    for (int mt = 0; mt < 4; ++mt) {
        #pragma unroll
        for (int r = 0; r < 4; ++r) {
            const int rg = brow + mt * 16 + quad * 4 + r;
            if (rg < N) {
                const int col = wave * 32 + lm;
                float* yp = y + (size_t)rg * 128 + col;
                yp[0]  = acc[mt][0][r];
                yp[16] = acc[mt][1][r];
            }
        }
    }
}

// ===========================================================================
// gemm2 inline butterfly: lane f holds h[f]; returns this lane's channel sum.
// ===========================================================================
__device__ __forceinline__ float gemm2_butterfly(float hv, float4 wl, float4 wr, int lane) {
    float p0 = hv * wl.x, p1 = hv * wl.y, p2 = hv * wl.z, p3 = hv * wl.w;
    float p4 = hv * wr.x, p5 = hv * wr.y, p6 = hv * wr.z, p7 = hv * wr.w;
    const bool b0 = (lane & 1) != 0;
    float s0_ = b0 ? p0 : p4;
    float s1_ = b0 ? p1 : p5;
    float s2_ = b0 ? p2 : p6;
    float s3_ = b0 ? p3 : p7;
    float q0 = (b0 ? p4 : p0) + __shfl_xor(s0_, 1, 64);
    float q1 = (b0 ? p5 : p1) + __shfl_xor(s1_, 1, 64);
    float q2 = (b0 ? p6 : p2) + __shfl_xor(s2_, 1, 64);
    float q3 = (b0 ? p7 : p3) + __shfl_xor(s3_, 1, 64);
    const bool b1b = (lane & 2) != 0;
    float t0 = b1b ? q0 : q2;
    float t1 = b1b ? q1 : q3;
    float r0 = (b1b ? q2 : q0) + __shfl_xor(t0, 2, 64);
    float r1 = (b1b ? q3 : q1) + __shfl_xor(t1, 2, 64);
    const bool b2 = (lane & 4) != 0;
    float u0 = b2 ? r0 : r1;
    float zv = (b2 ? r1 : r0) + __shfl_xor(u0, 4, 64);
    zv += __shfl_xor(zv, 8, 64);
    zv += __shfl_xor(zv, 16, 64);
    zv += __shfl_xor(zv, 32, 64);
    return zv;
}

// ===========================================================================
// fused1 v3: TWO nodes per wave + gather unrolled x4 -> 8 independent 256B
// y-row loads in flight per iteration (mean jm~4 -> one memory round for
// most waves). Per-node FP add order identical to v2 (pair steps + tails).
// ===========================================================================
__global__ __launch_bounds__(256) void fused1_kernel(
    const float* __restrict__ y, const int* __restrict__ cnt, const int* __restrict__ bucket,
    const float* __restrict__ b1, const float* __restrict__ W2l, const float* __restrict__ W2r,
    float* __restrict__ z, int N)
{
    const int wave = threadIdx.x >> 6;
    const int lane = threadIdx.x & 63;
    const int half = lane >> 5;          // 0 -> node A, 1 -> node B
    const int l5   = lane & 31;
    const int base = (blockIdx.x * 4 + wave) * 2;
    if (base >= N) return;
    const int iA = base;
    const bool hasB = (base + 1 < N);
    const int iB = hasB ? base + 1 : base;

    const int degA = cnt[iA];
    const int degB = cnt[iB];
    const int ddA = (degA < CAP) ? degA : CAP;
    const int ddB = (degB < CAP) ? degB : CAP;

    // one coalesced load: both nodes' neighbor lists (rows are contiguous)
    const int myn = bucket[(size_t)(half ? iB : iA) * CAP + l5];

    float accA = 0.f, accB = 0.f;
    const int jm = (ddA > ddB) ? ddA : ddB;
    for (int j = 0; j < jm; j += 4) {
        // indices for 4 slots x 2 nodes (clamped to safe row 0 when unused)
        const int sA0 = __shfl(myn, j,      64);
        const int sA1 = __shfl(myn, j + 1,  64);
        const int sA2 = __shfl(myn, j + 2,  64);
        const int sA3 = __shfl(myn, j + 3,  64);
        const int sB0 = __shfl(myn, 32 + j,     64);
        const int sB1 = __shfl(myn, 33 + j,     64);
        const int sB2 = __shfl(myn, 34 + j,     64);
        const int sB3 = __shfl(myn, 35 + j,     64);
        const int cA0 = (j     < ddA) ? sA0 : 0;
        const int cA1 = (j + 1 < ddA) ? sA1 : 0;
        const int cA2 = (j + 2 < ddA) ? sA2 : 0;
        const int cA3 = (j + 3 < ddA) ? sA3 : 0;
        const int cB0 = (j     < ddB) ? sB0 : 0;
        const int cB1 = (j + 1 < ddB) ? sB1 : 0;
        const int cB2 = (j + 2 < ddB) ? sB2 : 0;
        const int cB3 = (j + 3 < ddB) ? sB3 : 0;
        // 8 independent gathers (each one coalesced 256B wave load)
        const float vA0 = y[(size_t)cA0 * 128 + lane];
        const float vA1 = y[(size_t)cA1 * 128 + lane];
        const float vA2 = y[(size_t)cA2 * 128 + lane];
        const float vA3 = y[(size_t)cA3 * 128 + lane];
        const float vB0 = y[(size_t)cB0 * 128 + lane];
        const float vB1 = y[(size_t)cB1 * 128 + lane];
        const float vB2 = y[(size_t)cB2 * 128 + lane];
        const float vB3 = y[(size_t)cB3 * 128 + lane];
        // pair-step adds, identical order to the v2 j+=2 loop
        if (j + 1 < ddA)      accA += vA0 + vA1;
        else if (j < ddA)     accA += vA0;
        if (j + 1 < ddB)      accB += vB0 + vB1;
        else if (j < ddB)     accB += vB0;
        if (j + 3 < ddA)      accA += vA2 + vA3;
        else if (j + 2 < ddA) accA += vA2;
        if (j + 3 < ddB)      accB += vB2 + vB3;
        else if (j + 2 < ddB) accB += vB2;
    }

    const float dinvA = 1.0f / fmaxf((float)degA, 1.0f);
    const float dinvB = 1.0f / fmaxf((float)degB, 1.0f);
    const float bl = b1[lane];
    float vA = accA * dinvA + bl + y[(size_t)iA * 128 + 64 + lane];
    float vB = accB * dinvB + bl + y[(size_t)iB * 128 + 64 + lane];

    float ssA = vA * vA, ssB = vB * vB;
    #pragma unroll
    for (int m = 32; m >= 1; m >>= 1) {
        ssA += __shfl_xor(ssA, m, 64);
        ssB += __shfl_xor(ssB, m, 64);
    }
    const float invA = 1.0f / fmaxf(sqrtf(ssA), 1e-12f);
    const float invB = 1.0f / fmaxf(sqrtf(ssB), 1e-12f);
    const float hvA = fmaxf(vA * invA, 0.f);
    const float hvB = fmaxf(vB * invB, 0.f);

    const float4 wl = *(const float4*)(W2l + lane * 4);
    const float4 wr = *(const float4*)(W2r + lane * 4);
    const float zvA = gemm2_butterfly(hvA, wl, wr, lane);
    const float zvB = gemm2_butterfly(hvB, wl, wr, lane);

    const int ch = 4 * (lane & 1) + (lane & 2) + ((lane >> 2) & 1);
    if (lane < 8) {
        z[(size_t)iA * 8 + ch] = zvA;
        if (hasB) z[(size_t)iB * 8 + ch] = zvB;
    }
}

// ===========================================================================
// fused2 v2: batched 8-wide prefetch of neighbor z-rows into registers.
// ===========================================================================
__global__ void fused2_kernel(const float* __restrict__ z, const int* __restrict__ cnt,
                              const int* __restrict__ bucket, const float* __restrict__ b2,
                              float* __restrict__ out, int N)
{
    const int i = blockIdx.x * blockDim.x + threadIdx.x;
    if (i >= N) return;
    const int deg = cnt[i];
    const int dd = (deg < CAP) ? deg : CAP;

    float4 t[8];
    #pragma unroll
    for (int j = 0; j < 8; ++j) {
        int s = bucket[(size_t)i * CAP + ((j < dd) ? j : 0)];
        s = (j < dd) ? s : i;                    // safe address for unused slots
        t[j] = *(const float4*)(z + (size_t)s * 8);
    }

    float4 acc = make_float4(0.f, 0.f, 0.f, 0.f);
    #pragma unroll
    for (int j = 0; j < 8; ++j) {
        if (j < dd) {
            acc.x += t[j].x; acc.y += t[j].y; acc.z += t[j].z; acc.w += t[j].w;
        }
    }
    for (int j = 8; j < dd; ++j) {               // rare tail (P ~ 0.6%)
        const int s = bucket[(size_t)i * CAP + j];
        const float4 u = *(const float4*)(z + (size_t)s * 8);
        acc.x += u.x; acc.y += u.y; acc.z += u.z; acc.w += u.w;
    }

    const float dinv = 1.0f / fmaxf((float)deg, 1.0f);
    const float4 r  = *(const float4*)(z + (size_t)i * 8 + 4);
    const float4 bb = *(const float4*)(b2);
    float4 o;
    o.x = acc.x * dinv + bb.x + r.x;
    o.y = acc.y * dinv + bb.y + r.y;
    o.z = acc.z * dinv + bb.z + r.z;
    o.w = acc.w * dinv + bb.w + r.w;
    const float ss = o.x * o.x + o.y * o.y + o.z * o.z + o.w * o.w;
    const float inv = 1.0f / fmaxf(sqrtf(ss), 1e-12f);
    o.x *= inv; o.y *= inv; o.z *= inv; o.w *= inv;
    *(float4*)(out + (size_t)i * 4) = o;
}

// ===========================================================================
extern "C" void kernel_launch(void* const* d_in, const int* in_sizes, int n_in,
                              void* d_out, int out_size, void* d_ws, size_t ws_size,
                              hipStream_t stream)
{
    const float* x    = (const float*)d_in[0];
    const int*   ei   = (const int*)d_in[1];
    const float* W1l  = (const float*)d_in[2];
    const float* b1l  = (const float*)d_in[3];
    const float* W1r  = (const float*)d_in[4];
    const float* W2l  = (const float*)d_in[5];
    const float* b2l  = (const float*)d_in[6];
    const float* W2r  = (const float*)d_in[7];
    float* out = (float*)d_out;

    const int N = in_sizes[0] / DIN;
    const int E = in_sizes[1] / 2;
    const int* src = ei;
    const int* dst = ei + E;

    // workspace layout
    char* ws = (char*)d_ws;
    size_t woff = 0;
    auto alloc = [&](size_t bytes) {
        void* p = ws + woff;
        woff += (bytes + 255) & ~(size_t)255;
        return p;
    };
    float* y      = (float*)alloc((size_t)N * 128 * 4);
    float* z      = (float*)alloc((size_t)N * 8 * 4);
    short* WTh    = (short*)alloc((size_t)128 * 256 * 2);
    short* WTl    = (short*)alloc((size_t)128 * 256 * 2);
    int*   cnt    = (int*)alloc((size_t)N * 4);
    int*   bucket = (int*)alloc((size_t)N * CAP * 4);

    // --- dispatch 1: W prep + cnt zeroing (replaces hipMemsetAsync)
    const int ZB = ((N >> 2) + 255) / 256;
    wprep_zero_kernel<<<128 + ZB, 256, 0, stream>>>(W1l, W1r, WTh, WTl, cnt, N);

    // --- dispatch 2: layer-1 GEMM (leading blocks) + edge scatter (trailing)
    const int NB = (N + 63) / 64;
    const int SB = (E + 255) / 256;
    gemm_scatter_kernel<<<NB + SB, 256, 0, stream>>>(x, WTh, WTl, y,
                                                     src, dst, cnt, bucket, N, E, NB);

    // --- dispatch 3: fused aggregate + norm + relu + gemm2 (2 nodes/wave, x4 unroll)
    fused1_kernel<<<(N + 7) / 8, 256, 0, stream>>>(y, cnt, bucket, b1l, W2l, W2r, z, N);

    // --- dispatch 4: fused aggregate + norm (layer 2, batched prefetch)
    fused2_kernel<<<(N + 255) / 256, 256, 0, stream>>>(z, cnt, bucket, b2l, out, N);
}